// Round 6
// baseline (381.714 us; speedup 1.0000x reference)
//
#include <hip/hip_runtime.h>

// GCN graph classifier: 3x GCNConv(64->64, relu) + mean-pool + linear(64->10)
// N=100000 nodes, E=1600000 edges, 64 graphs.
//
// R5 -> R6: aggregate was traffic-bound (FETCH 193MB/dispatch at 3.6TB/s
// L2-fill; gather volume E x 256B = 410MB of f32 rows, working set 25.6MB
// >> 4MB/XCD L2). Hs (gather operand) now stored bf16 (RNE): rows 128B,
// gather volume halved. Accumulation, self-loop, bias, output all stay f32;
// mean-pool averages per-node quantization noise (est ~1e-4 << 2.4e-3).

#define HIDDEN 64
#define BSHIFT 8          // 256 nodes per bucket
#define MAXB 512          // LDS histogram capacity (NB = ceil(N/256) = 391)

__device__ __forceinline__ unsigned short f32_to_bf16_rne(float f) {
    unsigned u = __float_as_uint(f);
    u += 0x7FFF + ((u >> 16) & 1);
    return (unsigned short)(u >> 16);
}
__device__ __forceinline__ float bf16_to_f32(unsigned short h) {
    return __uint_as_float((unsigned)h << 16);
}

__global__ __launch_bounds__(256) void bucket_count(const int* __restrict__ dst,
                                                    int* __restrict__ gCount,
                                                    int E, int perBlock) {
    __shared__ int hist[MAXB];
    for (int i = threadIdx.x; i < MAXB; i += 256) hist[i] = 0;
    __syncthreads();
    int beg = blockIdx.x * perBlock;
    int end = min(beg + perBlock, E);
    if (beg < end) {
        int n4 = (end - beg) >> 2;
        const int4* d4 = reinterpret_cast<const int4*>(dst + beg);
        for (int g = threadIdx.x; g < n4; g += 256) {
            int4 d = d4[g];
            atomicAdd(&hist[d.x >> BSHIFT], 1);
            atomicAdd(&hist[d.y >> BSHIFT], 1);
            atomicAdd(&hist[d.z >> BSHIFT], 1);
            atomicAdd(&hist[d.w >> BSHIFT], 1);
        }
        for (int e = beg + (n4 << 2) + threadIdx.x; e < end; e += 256)
            atomicAdd(&hist[dst[e] >> BSHIFT], 1);
    }
    __syncthreads();
    for (int i = threadIdx.x; i < MAXB; i += 256)
        if (hist[i]) atomicAdd(&gCount[i], hist[i]);
}

__global__ __launch_bounds__(512) void bucket_scan(const int* __restrict__ gCount,
                                                   int* __restrict__ gBase,
                                                   int* __restrict__ gCursor,
                                                   int* __restrict__ rowptr,
                                                   int NB, int N, int E) {
    __shared__ int sc[512];
    int t = threadIdx.x;
    int v = (t < NB) ? gCount[t] : 0;
    sc[t] = v;
    __syncthreads();
    for (int off = 1; off < 512; off <<= 1) {
        int u = (t >= off) ? sc[t - off] : 0;
        __syncthreads();
        sc[t] += u;
        __syncthreads();
    }
    if (t < NB) { int b = sc[t] - v; gBase[t] = b; gCursor[t] = b; }
    if (t == 0) rowptr[N] = E;
}

// Packed record: (src << 8) | (dst & 255). src < 2^24 required (N=100000 ok).
__global__ __launch_bounds__(256) void bucket_scatter(const int* __restrict__ src,
                                                      const int* __restrict__ dst,
                                                      int* __restrict__ gCursor,
                                                      unsigned* __restrict__ rec,
                                                      int E, int perBlock) {
    __shared__ int hist[MAXB];
    __shared__ int cur[MAXB];
    for (int i = threadIdx.x; i < MAXB; i += 256) hist[i] = 0;
    __syncthreads();
    int beg = blockIdx.x * perBlock;
    int end = min(beg + perBlock, E);
    if (beg >= end) return;
    int n4 = (end - beg) >> 2;
    const int4* d4 = reinterpret_cast<const int4*>(dst + beg);
    const int4* s4 = reinterpret_cast<const int4*>(src + beg);
    for (int g = threadIdx.x; g < n4; g += 256) {
        int4 d = d4[g];
        atomicAdd(&hist[d.x >> BSHIFT], 1);
        atomicAdd(&hist[d.y >> BSHIFT], 1);
        atomicAdd(&hist[d.z >> BSHIFT], 1);
        atomicAdd(&hist[d.w >> BSHIFT], 1);
    }
    for (int e = beg + (n4 << 2) + threadIdx.x; e < end; e += 256)
        atomicAdd(&hist[dst[e] >> BSHIFT], 1);
    __syncthreads();
    for (int i = threadIdx.x; i < MAXB; i += 256)
        cur[i] = hist[i] ? atomicAdd(&gCursor[i], hist[i]) : 0;
    __syncthreads();
    for (int g = threadIdx.x; g < n4; g += 256) {
        int4 d = d4[g];
        int4 s = s4[g];
        int p;
        p = atomicAdd(&cur[d.x >> BSHIFT], 1); rec[p] = ((unsigned)s.x << 8) | (unsigned)(d.x & 255);
        p = atomicAdd(&cur[d.y >> BSHIFT], 1); rec[p] = ((unsigned)s.y << 8) | (unsigned)(d.y & 255);
        p = atomicAdd(&cur[d.z >> BSHIFT], 1); rec[p] = ((unsigned)s.z << 8) | (unsigned)(d.z & 255);
        p = atomicAdd(&cur[d.w >> BSHIFT], 1); rec[p] = ((unsigned)s.w << 8) | (unsigned)(d.w & 255);
    }
    for (int e = beg + (n4 << 2) + threadIdx.x; e < end; e += 256) {
        int d = dst[e];
        int p = atomicAdd(&cur[d >> BSHIFT], 1);
        rec[p] = ((unsigned)src[e] << 8) | (unsigned)(d & 255);
    }
}

// One block per bucket: local node histogram + scan -> rowptr/dinv (coalesced),
// then col scatter confined to this bucket's 16KB window.
__global__ __launch_bounds__(256) void bucket_build(const unsigned* __restrict__ rec,
                                                    const int* __restrict__ gBase,
                                                    const int* __restrict__ gCount,
                                                    int* __restrict__ rowptr,
                                                    float* __restrict__ dinv,
                                                    int* __restrict__ col, int N) {
    int b = blockIdx.x;
    int base = gBase[b], cnt = gCount[b];
    int t = threadIdx.x;
    __shared__ int hist[256];
    __shared__ int sc[256];
    __shared__ int cur[256];
    hist[t] = 0;
    __syncthreads();
    for (int i = base + t; i < base + cnt; i += 256)
        atomicAdd(&hist[rec[i] & 255], 1);
    __syncthreads();
    int myCnt = hist[t];
    sc[t] = myCnt;
    __syncthreads();
    for (int off = 1; off < 256; off <<= 1) {
        int u = (t >= off) ? sc[t - off] : 0;
        __syncthreads();
        sc[t] += u;
        __syncthreads();
    }
    int nodeBase = base + sc[t] - myCnt;   // exclusive
    int node = (b << BSHIFT) + t;
    if (node < N) {
        rowptr[node] = nodeBase;
        dinv[node] = rsqrtf((float)(myCnt + 1));
    }
    cur[t] = nodeBase;
    __syncthreads();
    for (int i = base + t; i < base + cnt; i += 256) {
        unsigned r = rec[i];
        int p = atomicAdd(&cur[r & 255], 1);
        col[p] = (int)(r >> 8);
    }
}

// Hs = bf16( dinv[row] * (X @ W) )  (X:[N,64] f32, W staged in LDS).
__global__ __launch_bounds__(256) void gemm64(const float* __restrict__ X,
                                              const float* __restrict__ W,
                                              const float* __restrict__ dinv,
                                              unsigned short* __restrict__ Hs, int N) {
    __shared__ float Ws[64 * 64];
    for (int i = threadIdx.x; i < 64 * 64; i += 256) Ws[i] = W[i];
    __syncthreads();
    int row = blockIdx.x * 256 + threadIdx.x;
    if (row >= N) return;
    const float4* xr = reinterpret_cast<const float4*>(X + (size_t)row * 64);
    const float4* Ws4 = reinterpret_cast<const float4*>(Ws);
    float4 acc[16];
#pragma unroll
    for (int j = 0; j < 16; j++) acc[j] = make_float4(0.f, 0.f, 0.f, 0.f);
#pragma unroll
    for (int k4 = 0; k4 < 16; k4++) {
        float4 xv = xr[k4];
#pragma unroll
        for (int kk = 0; kk < 4; kk++) {
            float xk = (&xv.x)[kk];
            int k = k4 * 4 + kk;
#pragma unroll
            for (int j = 0; j < 16; j++) {
                float4 w = Ws4[k * 16 + j];
                acc[j].x += xk * w.x;
                acc[j].y += xk * w.y;
                acc[j].z += xk * w.z;
                acc[j].w += xk * w.w;
            }
        }
    }
    float dn = dinv[row];
    // pack 64 bf16 = 8 x uint2 stores (coalesced 128B/row)
    uint2* hr = reinterpret_cast<uint2*>(Hs + (size_t)row * 64);
#pragma unroll
    for (int j2 = 0; j2 < 8; j2++) {
        float4 a = acc[2 * j2], b = acc[2 * j2 + 1];
        unsigned lo0 = f32_to_bf16_rne(dn * a.x) | ((unsigned)f32_to_bf16_rne(dn * a.y) << 16);
        unsigned lo1 = f32_to_bf16_rne(dn * a.z) | ((unsigned)f32_to_bf16_rne(dn * a.w) << 16);
        unsigned hi0 = f32_to_bf16_rne(dn * b.x) | ((unsigned)f32_to_bf16_rne(dn * b.y) << 16);
        unsigned hi1 = f32_to_bf16_rne(dn * b.z) | ((unsigned)f32_to_bf16_rne(dn * b.w) << 16);
        hr[2 * j2]     = make_uint2(lo0, lo1);
        hr[2 * j2 + 1] = make_uint2(hi0, hi1);
    }
}

// out[n,:] = relu( dinv[n] * (sum_e Hs[col[e],:] + Hs[n,:]) + b )  (Hs bf16)
// One wave per node; lane = channel; 8 independent row gathers in flight.
__global__ __launch_bounds__(256) void aggregate_kernel(const unsigned short* __restrict__ Hs,
                                                        const int* __restrict__ rowptr,
                                                        const int* __restrict__ col,
                                                        const float* __restrict__ dinv,
                                                        const float* __restrict__ bias,
                                                        float* __restrict__ OUT, int N) {
    int node = blockIdx.x * 4 + (threadIdx.x >> 6);
    int lane = threadIdx.x & 63;
    if (node >= N) return;
    int beg = __builtin_amdgcn_readfirstlane(rowptr[node]);
    int end = __builtin_amdgcn_readfirstlane(rowptr[node + 1]);
    float a0 = 0.f, a1 = 0.f, a2 = 0.f, a3 = 0.f;
    float a4 = 0.f, a5 = 0.f, a6 = 0.f, a7 = 0.f;
    int e = beg;
    for (; e + 8 <= end; e += 8) {
        int s0 = col[e],     s1 = col[e + 1], s2 = col[e + 2], s3 = col[e + 3];
        int s4 = col[e + 4], s5 = col[e + 5], s6 = col[e + 6], s7 = col[e + 7];
        unsigned short v0 = Hs[(size_t)s0 * 64 + lane];
        unsigned short v1 = Hs[(size_t)s1 * 64 + lane];
        unsigned short v2 = Hs[(size_t)s2 * 64 + lane];
        unsigned short v3 = Hs[(size_t)s3 * 64 + lane];
        unsigned short v4 = Hs[(size_t)s4 * 64 + lane];
        unsigned short v5 = Hs[(size_t)s5 * 64 + lane];
        unsigned short v6 = Hs[(size_t)s6 * 64 + lane];
        unsigned short v7 = Hs[(size_t)s7 * 64 + lane];
        a0 += bf16_to_f32(v0); a1 += bf16_to_f32(v1);
        a2 += bf16_to_f32(v2); a3 += bf16_to_f32(v3);
        a4 += bf16_to_f32(v4); a5 += bf16_to_f32(v5);
        a6 += bf16_to_f32(v6); a7 += bf16_to_f32(v7);
    }
    for (; e < end; e++) a0 += bf16_to_f32(Hs[(size_t)col[e] * 64 + lane]);
    float acc = ((a0 + a1) + (a2 + a3)) + ((a4 + a5) + (a6 + a7));
    acc += bf16_to_f32(Hs[(size_t)node * 64 + lane]);   // self loop (pre-scaled)
    acc = fmaxf(acc * dinv[node] + bias[lane], 0.f);
    OUT[(size_t)node * 64 + lane] = acc;
}

// One wave per 64 contiguous nodes; batch sorted -> few graph boundaries.
__global__ __launch_bounds__(256) void pool_partial(const float* __restrict__ H,
                                                    const int* __restrict__ batch,
                                                    float* __restrict__ sums, int N) {
    int wid = (blockIdx.x * blockDim.x + threadIdx.x) >> 6;
    int lane = threadIdx.x & 63;
    int start = wid * 64;
    if (start >= N) return;
    int end = min(start + 64, N);
    int g = batch[start];
    float acc = 0.f;
    for (int n = start; n < end; n++) {
        int bg = batch[n];
        if (bg != g) { atomicAdd(&sums[g * 64 + lane], acc); acc = 0.f; g = bg; }
        acc += H[(size_t)n * 64 + lane];
    }
    atomicAdd(&sums[g * 64 + lane], acc);
}

__device__ __forceinline__ int lower_bound_dev(const int* a, int n, int key) {
    int lo = 0, hi = n;
    while (lo < hi) { int mid = (lo + hi) >> 1; if (a[mid] < key) lo = mid + 1; else hi = mid; }
    return lo;
}

// out[g,c] = (sum_k sums[g,k]*Wc[k,c]) / cnt[g] + bc[c]
__global__ void classify_kernel(const float* __restrict__ sums, const float* __restrict__ Wc,
                                const float* __restrict__ bc, const int* __restrict__ batch,
                                float* __restrict__ out, int N) {
    int t = blockIdx.x * blockDim.x + threadIdx.x;
    if (t >= 64 * 10) return;
    int g = t / 10, c = t % 10;
    float acc = 0.f;
    for (int k = 0; k < 64; k++) acc += sums[g * 64 + k] * Wc[k * 10 + c];
    int cnt = lower_bound_dev(batch, N, g + 1) - lower_bound_dev(batch, N, g);
    out[t] = acc / (float)max(cnt, 1) + bc[c];
}

extern "C" void kernel_launch(void* const* d_in, const int* in_sizes, int n_in,
                              void* d_out, int out_size, void* d_ws, size_t ws_size,
                              hipStream_t stream) {
    const float* x  = (const float*)d_in[0];
    const int* ei   = (const int*)d_in[1];
    const int* batch= (const int*)d_in[2];
    const float* W1 = (const float*)d_in[3];
    const float* b1 = (const float*)d_in[4];
    const float* W2 = (const float*)d_in[5];
    const float* b2 = (const float*)d_in[6];
    const float* W3 = (const float*)d_in[7];
    const float* b3 = (const float*)d_in[8];
    const float* Wc = (const float*)d_in[9];
    const float* bc = (const float*)d_in[10];

    int N = in_sizes[0] / HIDDEN;
    int E = in_sizes[1] / 2;
    const int* src = ei;
    const int* dst = ei + E;
    int NB = (N + 255) >> 8;              // buckets of 256 nodes (<= MAXB)

    char* ws = (char*)d_ws;
    size_t off = 0;
    auto alloc = [&](size_t bytes) { void* p = ws + off; off = (off + bytes + 255) & ~(size_t)255; return p; };
    int*   gCount = (int*)  alloc((size_t)MAXB * 4);
    int*   gBase  = (int*)  alloc((size_t)MAXB * 4);
    int*   gCursor= (int*)  alloc((size_t)MAXB * 4);
    int*   rowptr = (int*)  alloc((size_t)(N + 1) * 4);
    float* dinv   = (float*)alloc((size_t)N * 4);
    int*   col    = (int*)  alloc((size_t)E * 4);
    unsigned short* hb = (unsigned short*)alloc((size_t)N * HIDDEN * 2);  // bf16 gemm out
    float* hf     = (float*)alloc((size_t)N * HIDDEN * 4);                // f32 agg out
    float* sums   = (float*)alloc(64 * 64 * 4);
    unsigned* rec = (unsigned*)hf;        // aliased: consumed (bucket_build) before aggregate1 writes hf

    // ---- CSR build (2-level counting sort) ----
    int grid = 256;
    int perBlock = (((E + grid - 1) / grid) + 3) & ~3;
    hipMemsetAsync(gCount, 0, (size_t)MAXB * 4, stream);
    hipMemsetAsync(sums, 0, 64 * 64 * 4, stream);
    bucket_count<<<grid, 256, 0, stream>>>(dst, gCount, E, perBlock);
    bucket_scan<<<1, 512, 0, stream>>>(gCount, gBase, gCursor, rowptr, NB, N, E);
    bucket_scatter<<<grid, 256, 0, stream>>>(src, dst, gCursor, rec, E, perBlock);
    bucket_build<<<NB, 256, 0, stream>>>(rec, gBase, gCount, rowptr, dinv, col, N);

    // ---- 3 GCN layers ----
    int gGemm = (N + 255) / 256;
    int gAgg  = (N + 3) / 4;
    gemm64<<<gGemm, 256, 0, stream>>>(x, W1, dinv, hb, N);
    aggregate_kernel<<<gAgg, 256, 0, stream>>>(hb, rowptr, col, dinv, b1, hf, N);
    gemm64<<<gGemm, 256, 0, stream>>>(hf, W2, dinv, hb, N);
    aggregate_kernel<<<gAgg, 256, 0, stream>>>(hb, rowptr, col, dinv, b2, hf, N);
    gemm64<<<gGemm, 256, 0, stream>>>(hf, W3, dinv, hb, N);
    aggregate_kernel<<<gAgg, 256, 0, stream>>>(hb, rowptr, col, dinv, b3, hf, N);

    // ---- pool + classify ----
    pool_partial<<<(N + 255) / 256, 256, 0, stream>>>(hf, batch, sums, N);
    classify_kernel<<<1, 640, 0, stream>>>(sums, Wc, bc, batch, (float*)d_out, N);
}

// Round 7
// 290.794 us; speedup vs baseline: 1.3127x; 1.3127x over previous
//
#include <hip/hip_runtime.h>

// GCN graph classifier: 3x GCNConv(64->64, relu) + mean-pool + linear(64->10)
// N=100000 nodes, E=1600000 edges, 64 graphs.
//
// R6 -> R7: gemm64 was occupancy- and LDS-bound (391 blocks = 1.5/CU, 16KB
// LDS read per output row -> 53us x3). Replaced by MFMA gemm:
//  - activations bf16 (input cast adds only per-node random error, averaged
//    out by the 1500-node mean pool; gemm OUTPUT was already bf16 for R6's
//    gather optimization)
//  - W split hi/lo bf16 (W error is systematic across nodes -> pooling can't
//    average it; hi/lo split makes the GEMM ~f32-accurate): 2 MFMAs/tile
//  - mfma_f32_16x16x32_bf16, C/D layout col=lane&15,row=(lane>>4)*4+reg
//  - aggregate writes bf16 (consumer casts anyway; halves write traffic)

#define HIDDEN 64
#define BSHIFT 8          // 256 nodes per bucket
#define MAXB 512          // LDS histogram capacity (NB = ceil(N/256) = 391)

typedef __attribute__((ext_vector_type(8))) short bf16x8;
typedef __attribute__((ext_vector_type(4))) float f32x4;

__device__ __forceinline__ unsigned short f32_to_bf16_rne(float f) {
    unsigned u = __float_as_uint(f);
    u += 0x7FFF + ((u >> 16) & 1);
    return (unsigned short)(u >> 16);
}
__device__ __forceinline__ float bf16_to_f32(unsigned short h) {
    return __uint_as_float((unsigned)h << 16);
}

__global__ __launch_bounds__(256) void bucket_count(const int* __restrict__ dst,
                                                    int* __restrict__ gCount,
                                                    int E, int perBlock) {
    __shared__ int hist[MAXB];
    for (int i = threadIdx.x; i < MAXB; i += 256) hist[i] = 0;
    __syncthreads();
    int beg = blockIdx.x * perBlock;
    int end = min(beg + perBlock, E);
    if (beg < end) {
        int n4 = (end - beg) >> 2;
        const int4* d4 = reinterpret_cast<const int4*>(dst + beg);
        for (int g = threadIdx.x; g < n4; g += 256) {
            int4 d = d4[g];
            atomicAdd(&hist[d.x >> BSHIFT], 1);
            atomicAdd(&hist[d.y >> BSHIFT], 1);
            atomicAdd(&hist[d.z >> BSHIFT], 1);
            atomicAdd(&hist[d.w >> BSHIFT], 1);
        }
        for (int e = beg + (n4 << 2) + threadIdx.x; e < end; e += 256)
            atomicAdd(&hist[dst[e] >> BSHIFT], 1);
    }
    __syncthreads();
    for (int i = threadIdx.x; i < MAXB; i += 256)
        if (hist[i]) atomicAdd(&gCount[i], hist[i]);
}

__global__ __launch_bounds__(512) void bucket_scan(const int* __restrict__ gCount,
                                                   int* __restrict__ gBase,
                                                   int* __restrict__ gCursor,
                                                   int* __restrict__ rowptr,
                                                   int NB, int N, int E) {
    __shared__ int sc[512];
    int t = threadIdx.x;
    int v = (t < NB) ? gCount[t] : 0;
    sc[t] = v;
    __syncthreads();
    for (int off = 1; off < 512; off <<= 1) {
        int u = (t >= off) ? sc[t - off] : 0;
        __syncthreads();
        sc[t] += u;
        __syncthreads();
    }
    if (t < NB) { int b = sc[t] - v; gBase[t] = b; gCursor[t] = b; }
    if (t == 0) rowptr[N] = E;
}

// Packed record: (src << 8) | (dst & 255). src < 2^24 required (N=100000 ok).
__global__ __launch_bounds__(256) void bucket_scatter(const int* __restrict__ src,
                                                      const int* __restrict__ dst,
                                                      int* __restrict__ gCursor,
                                                      unsigned* __restrict__ rec,
                                                      int E, int perBlock) {
    __shared__ int hist[MAXB];
    __shared__ int cur[MAXB];
    for (int i = threadIdx.x; i < MAXB; i += 256) hist[i] = 0;
    __syncthreads();
    int beg = blockIdx.x * perBlock;
    int end = min(beg + perBlock, E);
    if (beg >= end) return;
    int n4 = (end - beg) >> 2;
    const int4* d4 = reinterpret_cast<const int4*>(dst + beg);
    const int4* s4 = reinterpret_cast<const int4*>(src + beg);
    for (int g = threadIdx.x; g < n4; g += 256) {
        int4 d = d4[g];
        atomicAdd(&hist[d.x >> BSHIFT], 1);
        atomicAdd(&hist[d.y >> BSHIFT], 1);
        atomicAdd(&hist[d.z >> BSHIFT], 1);
        atomicAdd(&hist[d.w >> BSHIFT], 1);
    }
    for (int e = beg + (n4 << 2) + threadIdx.x; e < end; e += 256)
        atomicAdd(&hist[dst[e] >> BSHIFT], 1);
    __syncthreads();
    for (int i = threadIdx.x; i < MAXB; i += 256)
        cur[i] = hist[i] ? atomicAdd(&gCursor[i], hist[i]) : 0;
    __syncthreads();
    for (int g = threadIdx.x; g < n4; g += 256) {
        int4 d = d4[g];
        int4 s = s4[g];
        int p;
        p = atomicAdd(&cur[d.x >> BSHIFT], 1); rec[p] = ((unsigned)s.x << 8) | (unsigned)(d.x & 255);
        p = atomicAdd(&cur[d.y >> BSHIFT], 1); rec[p] = ((unsigned)s.y << 8) | (unsigned)(d.y & 255);
        p = atomicAdd(&cur[d.z >> BSHIFT], 1); rec[p] = ((unsigned)s.z << 8) | (unsigned)(d.z & 255);
        p = atomicAdd(&cur[d.w >> BSHIFT], 1); rec[p] = ((unsigned)s.w << 8) | (unsigned)(d.w & 255);
    }
    for (int e = beg + (n4 << 2) + threadIdx.x; e < end; e += 256) {
        int d = dst[e];
        int p = atomicAdd(&cur[d >> BSHIFT], 1);
        rec[p] = ((unsigned)src[e] << 8) | (unsigned)(d & 255);
    }
}

// One block per bucket: local node histogram + scan -> rowptr/dinv (coalesced),
// then col scatter confined to this bucket's 16KB window.
__global__ __launch_bounds__(256) void bucket_build(const unsigned* __restrict__ rec,
                                                    const int* __restrict__ gBase,
                                                    const int* __restrict__ gCount,
                                                    int* __restrict__ rowptr,
                                                    float* __restrict__ dinv,
                                                    int* __restrict__ col, int N) {
    int b = blockIdx.x;
    int base = gBase[b], cnt = gCount[b];
    int t = threadIdx.x;
    __shared__ int hist[256];
    __shared__ int sc[256];
    __shared__ int cur[256];
    hist[t] = 0;
    __syncthreads();
    for (int i = base + t; i < base + cnt; i += 256)
        atomicAdd(&hist[rec[i] & 255], 1);
    __syncthreads();
    int myCnt = hist[t];
    sc[t] = myCnt;
    __syncthreads();
    for (int off = 1; off < 256; off <<= 1) {
        int u = (t >= off) ? sc[t - off] : 0;
        __syncthreads();
        sc[t] += u;
        __syncthreads();
    }
    int nodeBase = base + sc[t] - myCnt;   // exclusive
    int node = (b << BSHIFT) + t;
    if (node < N) {
        rowptr[node] = nodeBase;
        dinv[node] = rsqrtf((float)(myCnt + 1));
    }
    cur[t] = nodeBase;
    __syncthreads();
    for (int i = base + t; i < base + cnt; i += 256) {
        unsigned r = rec[i];
        int p = atomicAdd(&cur[r & 255], 1);
        col[p] = (int)(r >> 8);
    }
}

// x (f32) -> xb (bf16), 8 elements/thread.
__global__ void cast_kernel(const float* __restrict__ x, unsigned short* __restrict__ xb, int n8) {
    int i = blockIdx.x * blockDim.x + threadIdx.x;
    if (i >= n8) return;
    const float4* p = reinterpret_cast<const float4*>(x) + 2 * (size_t)i;
    float4 a = p[0], b = p[1];
    unsigned v0 = f32_to_bf16_rne(a.x) | ((unsigned)f32_to_bf16_rne(a.y) << 16);
    unsigned v1 = f32_to_bf16_rne(a.z) | ((unsigned)f32_to_bf16_rne(a.w) << 16);
    unsigned v2 = f32_to_bf16_rne(b.x) | ((unsigned)f32_to_bf16_rne(b.y) << 16);
    unsigned v3 = f32_to_bf16_rne(b.z) | ((unsigned)f32_to_bf16_rne(b.w) << 16);
    reinterpret_cast<uint4*>(xb)[i] = make_uint4(v0, v1, v2, v3);
}

// Hs = bf16( dinv[row] * (Xb @ (Wh+Wl)) )  via mfma_f32_16x16x32_bf16.
// Block = 64 rows, 4 waves x 16 rows. W staged hi/lo TRANSPOSED in LDS so
// B-fragments (col=lane&15, k=(lane>>4)*8+j) are contiguous 16B reads.
// Rows padded +8 bf16 (16B) -> 2-way LDS conflicts only (free).
__global__ __launch_bounds__(256) void gemm_mfma(const unsigned short* __restrict__ Xb,
                                                 const float* __restrict__ W,
                                                 const float* __restrict__ dinv,
                                                 unsigned short* __restrict__ Hs, int N) {
    __shared__ __align__(16) unsigned short A_t[64][72];
    __shared__ __align__(16) unsigned short Wh_t[64][72];
    __shared__ __align__(16) unsigned short Wl_t[64][72];
    int t = threadIdx.x;
    int rowBase = blockIdx.x * 64;
    // stage W split hi/lo, transposed: Wt[col][k]
    for (int i = t; i < 4096; i += 256) {
        int k = i >> 6, c = i & 63;
        float w = W[i];
        unsigned short h = f32_to_bf16_rne(w);
        float rem = w - bf16_to_f32(h);
        Wh_t[c][k] = h;
        Wl_t[c][k] = f32_to_bf16_rne(rem);
    }
    // stage A tile: 64 rows x 128B, 16B chunks
    for (int c = t; c < 512; c += 256) {
        int r = c >> 3, kc = c & 7;
        int rr = min(rowBase + r, N - 1);
        uint4 v = reinterpret_cast<const uint4*>(Xb + ((size_t)rr << 6))[kc];
        *reinterpret_cast<uint4*>(&A_t[r][kc * 8]) = v;
    }
    __syncthreads();
    int w = t >> 6, lane = t & 63;
    int lr = lane & 15, lk = lane >> 4;
    int arow = w * 16 + lr;
    f32x4 zero = {0.f, 0.f, 0.f, 0.f};
    f32x4 acc[4];
    acc[0] = zero; acc[1] = zero; acc[2] = zero; acc[3] = zero;
    bf16x8 a0 = *reinterpret_cast<const bf16x8*>(&A_t[arow][lk * 8]);
    bf16x8 a1 = *reinterpret_cast<const bf16x8*>(&A_t[arow][32 + lk * 8]);
#pragma unroll
    for (int ct = 0; ct < 4; ct++) {
        int bcol = ct * 16 + lr;
        bf16x8 bh0 = *reinterpret_cast<const bf16x8*>(&Wh_t[bcol][lk * 8]);
        bf16x8 bl0 = *reinterpret_cast<const bf16x8*>(&Wl_t[bcol][lk * 8]);
        bf16x8 bh1 = *reinterpret_cast<const bf16x8*>(&Wh_t[bcol][32 + lk * 8]);
        bf16x8 bl1 = *reinterpret_cast<const bf16x8*>(&Wl_t[bcol][32 + lk * 8]);
        acc[ct] = __builtin_amdgcn_mfma_f32_16x16x32_bf16(a0, bh0, acc[ct], 0, 0, 0);
        acc[ct] = __builtin_amdgcn_mfma_f32_16x16x32_bf16(a0, bl0, acc[ct], 0, 0, 0);
        acc[ct] = __builtin_amdgcn_mfma_f32_16x16x32_bf16(a1, bh1, acc[ct], 0, 0, 0);
        acc[ct] = __builtin_amdgcn_mfma_f32_16x16x32_bf16(a1, bl1, acc[ct], 0, 0, 0);
    }
    // epilogue: C/D layout col=lane&15, row=(lane>>4)*4+reg
#pragma unroll
    for (int i = 0; i < 4; i++) {
        int row = rowBase + w * 16 + lk * 4 + i;
        if (row < N) {
            float dn = dinv[row];
#pragma unroll
            for (int ct = 0; ct < 4; ct++) {
                Hs[(size_t)row * 64 + ct * 16 + lr] = f32_to_bf16_rne(dn * acc[ct][i]);
            }
        }
    }
}

// out[n,:] = bf16( relu( dinv[n] * (sum_e Hs[col[e],:] + Hs[n,:]) + b ) )
// One wave per node; lane = channel; 8 independent row gathers in flight.
__global__ __launch_bounds__(256) void aggregate_kernel(const unsigned short* __restrict__ Hs,
                                                        const int* __restrict__ rowptr,
                                                        const int* __restrict__ col,
                                                        const float* __restrict__ dinv,
                                                        const float* __restrict__ bias,
                                                        unsigned short* __restrict__ OUT, int N) {
    int node = blockIdx.x * 4 + (threadIdx.x >> 6);
    int lane = threadIdx.x & 63;
    if (node >= N) return;
    int beg = __builtin_amdgcn_readfirstlane(rowptr[node]);
    int end = __builtin_amdgcn_readfirstlane(rowptr[node + 1]);
    float a0 = 0.f, a1 = 0.f, a2 = 0.f, a3 = 0.f;
    float a4 = 0.f, a5 = 0.f, a6 = 0.f, a7 = 0.f;
    int e = beg;
    for (; e + 8 <= end; e += 8) {
        int s0 = col[e],     s1 = col[e + 1], s2 = col[e + 2], s3 = col[e + 3];
        int s4 = col[e + 4], s5 = col[e + 5], s6 = col[e + 6], s7 = col[e + 7];
        unsigned short v0 = Hs[(size_t)s0 * 64 + lane];
        unsigned short v1 = Hs[(size_t)s1 * 64 + lane];
        unsigned short v2 = Hs[(size_t)s2 * 64 + lane];
        unsigned short v3 = Hs[(size_t)s3 * 64 + lane];
        unsigned short v4 = Hs[(size_t)s4 * 64 + lane];
        unsigned short v5 = Hs[(size_t)s5 * 64 + lane];
        unsigned short v6 = Hs[(size_t)s6 * 64 + lane];
        unsigned short v7 = Hs[(size_t)s7 * 64 + lane];
        a0 += bf16_to_f32(v0); a1 += bf16_to_f32(v1);
        a2 += bf16_to_f32(v2); a3 += bf16_to_f32(v3);
        a4 += bf16_to_f32(v4); a5 += bf16_to_f32(v5);
        a6 += bf16_to_f32(v6); a7 += bf16_to_f32(v7);
    }
    for (; e < end; e++) a0 += bf16_to_f32(Hs[(size_t)col[e] * 64 + lane]);
    float acc = ((a0 + a1) + (a2 + a3)) + ((a4 + a5) + (a6 + a7));
    acc += bf16_to_f32(Hs[(size_t)node * 64 + lane]);   // self loop (pre-scaled)
    acc = fmaxf(acc * dinv[node] + bias[lane], 0.f);
    OUT[(size_t)node * 64 + lane] = f32_to_bf16_rne(acc);
}

// One wave per 64 contiguous nodes; batch sorted -> few graph boundaries.
__global__ __launch_bounds__(256) void pool_partial(const unsigned short* __restrict__ H,
                                                    const int* __restrict__ batch,
                                                    float* __restrict__ sums, int N) {
    int wid = (blockIdx.x * blockDim.x + threadIdx.x) >> 6;
    int lane = threadIdx.x & 63;
    int start = wid * 64;
    if (start >= N) return;
    int end = min(start + 64, N);
    int g = batch[start];
    float acc = 0.f;
    for (int n = start; n < end; n++) {
        int bg = batch[n];
        if (bg != g) { atomicAdd(&sums[g * 64 + lane], acc); acc = 0.f; g = bg; }
        acc += bf16_to_f32(H[(size_t)n * 64 + lane]);
    }
    atomicAdd(&sums[g * 64 + lane], acc);
}

__device__ __forceinline__ int lower_bound_dev(const int* a, int n, int key) {
    int lo = 0, hi = n;
    while (lo < hi) { int mid = (lo + hi) >> 1; if (a[mid] < key) lo = mid + 1; else hi = mid; }
    return lo;
}

// out[g,c] = (sum_k sums[g,k]*Wc[k,c]) / cnt[g] + bc[c]
__global__ void classify_kernel(const float* __restrict__ sums, const float* __restrict__ Wc,
                                const float* __restrict__ bc, const int* __restrict__ batch,
                                float* __restrict__ out, int N) {
    int t = blockIdx.x * blockDim.x + threadIdx.x;
    if (t >= 64 * 10) return;
    int g = t / 10, c = t % 10;
    float acc = 0.f;
    for (int k = 0; k < 64; k++) acc += sums[g * 64 + k] * Wc[k * 10 + c];
    int cnt = lower_bound_dev(batch, N, g + 1) - lower_bound_dev(batch, N, g);
    out[t] = acc / (float)max(cnt, 1) + bc[c];
}

extern "C" void kernel_launch(void* const* d_in, const int* in_sizes, int n_in,
                              void* d_out, int out_size, void* d_ws, size_t ws_size,
                              hipStream_t stream) {
    const float* x  = (const float*)d_in[0];
    const int* ei   = (const int*)d_in[1];
    const int* batch= (const int*)d_in[2];
    const float* W1 = (const float*)d_in[3];
    const float* b1 = (const float*)d_in[4];
    const float* W2 = (const float*)d_in[5];
    const float* b2 = (const float*)d_in[6];
    const float* W3 = (const float*)d_in[7];
    const float* b3 = (const float*)d_in[8];
    const float* Wc = (const float*)d_in[9];
    const float* bc = (const float*)d_in[10];

    int N = in_sizes[0] / HIDDEN;
    int E = in_sizes[1] / 2;
    const int* src = ei;
    const int* dst = ei + E;
    int NB = (N + 255) >> 8;              // buckets of 256 nodes (<= MAXB)

    char* ws = (char*)d_ws;
    size_t off = 0;
    auto alloc = [&](size_t bytes) { void* p = ws + off; off = (off + bytes + 255) & ~(size_t)255; return p; };
    int*   gCount = (int*)  alloc((size_t)MAXB * 4);
    int*   gBase  = (int*)  alloc((size_t)MAXB * 4);
    int*   gCursor= (int*)  alloc((size_t)MAXB * 4);
    int*   rowptr = (int*)  alloc((size_t)(N + 1) * 4);
    float* dinv   = (float*)alloc((size_t)N * 4);
    int*   col    = (int*)  alloc((size_t)E * 4);
    unsigned short* xb = (unsigned short*)alloc((size_t)N * HIDDEN * 2);  // bf16 x
    unsigned short* hb = (unsigned short*)alloc((size_t)N * HIDDEN * 2);  // bf16 gemm out
    unsigned short* ha = (unsigned short*)alloc((size_t)N * HIDDEN * 2);  // bf16 agg out
    float* sums   = (float*)alloc(64 * 64 * 4);
    unsigned* rec = (unsigned*)hb;        // aliased: consumed (bucket_build) before gemm1 writes hb

    // ---- CSR build (2-level counting sort) ----
    int grid = 256;
    int perBlock = (((E + grid - 1) / grid) + 3) & ~3;
    hipMemsetAsync(gCount, 0, (size_t)MAXB * 4, stream);
    hipMemsetAsync(sums, 0, 64 * 64 * 4, stream);
    bucket_count<<<grid, 256, 0, stream>>>(dst, gCount, E, perBlock);
    bucket_scan<<<1, 512, 0, stream>>>(gCount, gBase, gCursor, rowptr, NB, N, E);
    bucket_scatter<<<grid, 256, 0, stream>>>(src, dst, gCursor, rec, E, perBlock);
    bucket_build<<<NB, 256, 0, stream>>>(rec, gBase, gCount, rowptr, dinv, col, N);

    // ---- input cast ----
    int n8 = N * HIDDEN / 8;
    cast_kernel<<<(n8 + 255) / 256, 256, 0, stream>>>(x, xb, n8);

    // ---- 3 GCN layers ----
    int gGemm = (N + 63) / 64;
    int gAgg  = (N + 3) / 4;
    gemm_mfma<<<gGemm, 256, 0, stream>>>(xb, W1, dinv, hb, N);
    aggregate_kernel<<<gAgg, 256, 0, stream>>>(hb, rowptr, col, dinv, b1, ha, N);
    gemm_mfma<<<gGemm, 256, 0, stream>>>(ha, W2, dinv, hb, N);
    aggregate_kernel<<<gAgg, 256, 0, stream>>>(hb, rowptr, col, dinv, b2, ha, N);
    gemm_mfma<<<gGemm, 256, 0, stream>>>(ha, W3, dinv, hb, N);
    aggregate_kernel<<<gAgg, 256, 0, stream>>>(hb, rowptr, col, dinv, b3, ha, N);

    // ---- pool + classify ----
    pool_partial<<<(N + 255) / 256, 256, 0, stream>>>(ha, batch, sums, N);
    classify_kernel<<<1, 640, 0, stream>>>(sums, Wc, bc, batch, (float*)d_out, N);
}